// Round 3
// baseline (645.310 us; speedup 1.0000x reference)
//
#include <hip/hip_runtime.h>
#include <cstdint>

// Problem: B=64, T=512, I=K=1024, H=1024.
// Reference collapses to: rtot_z = h0@R_z^T + rb_z + b_z  (z in {f,i,g}; o-gate dead)
//   gate_z[m',h] = x_perm[m'] . W_z^T + rtot_z[b,h]   with m' = t*64 + b
//   c = sig(f)*c0 + sig(i)*tanh(g); hidden[h, m'] = tanh(c); last-t -> h_last, c_last.
//
// v4 this round: lstm_main3 = 8-wave (512 thr) 256m x 64h x 3-gate tile, BK=64,
// double-buffered LDS (112 KB), m201-style phased schedule:
//   per kt: 3 phases (one gate each, 16 MFMA clusters), raw s_barrier (NO
//   __syncthreads drain), staging for kt+1 issued early (phase 0/1/2 split),
//   ONE manual s_waitcnt vmcnt(0) per kt (loads had ~2 phases to land),
//   s_setprio(1) around MFMA clusters. T2 XOR swizzle kept (pays under phases).
// prep_fused unchanged (~65us). ~220us/iter is fixed harness reset overhead.

typedef short s16x8 __attribute__((ext_vector_type(8)));
typedef short s16x4 __attribute__((ext_vector_type(4)));
typedef float f32x4 __attribute__((ext_vector_type(4)));

static __device__ __forceinline__ float bf2f(unsigned short u) {
    union { unsigned int i; float f; } v; v.i = ((unsigned int)u) << 16; return v.f;
}
static __device__ __forceinline__ unsigned short f2bf(float f) {
    union { float f; unsigned int i; } v; v.f = f;
    unsigned int u = v.i;
    return (unsigned short)((u + 0x7fffu + ((u >> 16) & 1u)) >> 16);
}
static __device__ __forceinline__ float sigm_(float x) { return 1.0f / (1.0f + __expf(-x)); }
static __device__ __forceinline__ float tanh_(float x) { return 1.0f - 2.0f / (1.0f + __expf(2.0f * x)); }

// Detect fp32 vs bf16 storage (wave-uniform, deterministic).
static __device__ __forceinline__ int detect_f32(const void* x) {
    const unsigned int* u = (const unsigned int*)x;
    int c = 0;
#pragma unroll
    for (int i = 0; i < 16; ++i) {
        unsigned int e = (u[i] >> 23) & 255u;
        c += (e >= 100u && e <= 140u) ? 1 : 0;
    }
    return c >= 8;
}

static __device__ __forceinline__ float ldsc(const void* p, int i, int f32) {
    return f32 ? ((const float*)p)[i] : bf2f(((const unsigned short*)p)[i]);
}

static __device__ __forceinline__ float4 load4f(const void* p, size_t eoff, int f32) {
    if (f32) return *(const float4*)((const float*)p + eoff);
    s16x4 v = *(const s16x4*)((const unsigned short*)p + eoff);
    return make_float4(bf2f((unsigned short)v[0]), bf2f((unsigned short)v[1]),
                       bf2f((unsigned short)v[2]), bf2f((unsigned short)v[3]));
}

// 16B direct global->LDS. LDS dest linear in lane order (uniform base + lane*16).
static __device__ __forceinline__ void gl_lds16(const void* g, void* l) {
    __builtin_amdgcn_global_load_lds(
        (const __attribute__((address_space(1))) unsigned int*)g,
        (__attribute__((address_space(3))) unsigned int*)l, 16, 0, 0);
}

// ---------------- fused prep: linear bf16 convert of x,W  +  rprep ----------------
__global__ __launch_bounds__(256) void prep_fused(
    const void* __restrict__ x,
    const void* __restrict__ Wf, const void* __restrict__ Wi, const void* __restrict__ Wg,
    const void* __restrict__ h0,
    const void* __restrict__ Rf, const void* __restrict__ rbf, const void* __restrict__ bf_,
    const void* __restrict__ Ri, const void* __restrict__ rbi, const void* __restrict__ bi_,
    const void* __restrict__ Rg, const void* __restrict__ rbg, const void* __restrict__ bg_,
    unsigned short* __restrict__ xb, unsigned short* __restrict__ wb,
    float* __restrict__ rt)
{
    __shared__ float h0l[64][132];
    __shared__ float Rl[16][132];
    const int f32 = detect_f32(x);
    const int tid = threadIdx.x;
    const int bid = blockIdx.x;

    if (bid < 17920) {
        const int r = bid * 2 + (tid >> 7);
        const int c = (tid & 127) << 3;
        const void* src;
        size_t soff;
        unsigned short* dst;
        if (r < 32768) {
            src = x;
            soff = ((size_t)r << 10) + c;
            dst = xb + soff;
        } else {
            const int wr = r - 32768;
            const int g = wr >> 10;
            src = (g == 0) ? Wf : (g == 1) ? Wi : Wg;
            soff = ((size_t)(wr & 1023) << 10) + c;
            dst = wb + ((size_t)wr << 10) + c;
        }
        if (f32) {
            const float* s = (const float*)src + soff;
            float4 u0 = *(const float4*)s;
            float4 u1 = *(const float4*)(s + 4);
            s16x8 v;
            v[0] = (short)f2bf(u0.x); v[1] = (short)f2bf(u0.y);
            v[2] = (short)f2bf(u0.z); v[3] = (short)f2bf(u0.w);
            v[4] = (short)f2bf(u1.x); v[5] = (short)f2bf(u1.y);
            v[6] = (short)f2bf(u1.z); v[7] = (short)f2bf(u1.w);
            *(s16x8*)dst = v;
        } else {
            *(s16x8*)dst = *(const s16x8*)((const unsigned short*)src + soff);
        }
        return;
    }

    const int pb = bid - 17920;
    const int z  = pb >> 6;
    const int hb = (pb & 63) * 16;
    const void* R  = (z == 0) ? Rf  : (z == 1) ? Ri  : Rg;
    const void* rb = (z == 0) ? rbf : (z == 1) ? rbi : rbg;
    const void* bb = (z == 0) ? bf_ : (z == 1) ? bi_ : bg_;
    const int hl = tid >> 4;
    const int bq = tid & 15;
    float acc[4] = {0.f, 0.f, 0.f, 0.f};

    for (int k0 = 0; k0 < 1024; k0 += 128) {
#pragma unroll
        for (int i = 0; i < 8; ++i) {
            int lin = i * 256 + tid;
            int r = lin >> 5, c4 = lin & 31;
            *(float4*)&h0l[r][c4 * 4] = load4f(h0, (size_t)r * 1024 + k0 + c4 * 4, f32);
        }
#pragma unroll
        for (int i = 0; i < 2; ++i) {
            int lin = i * 256 + tid;
            int r = lin >> 5, c4 = lin & 31;
            *(float4*)&Rl[r][c4 * 4] = load4f(R, (size_t)(hb + r) * 1024 + k0 + c4 * 4, f32);
        }
        __syncthreads();
#pragma unroll 8
        for (int k4 = 0; k4 < 32; ++k4) {
            float4 rv = *(const float4*)&Rl[hl][k4 * 4];
#pragma unroll
            for (int j = 0; j < 4; ++j) {
                float4 hv = *(const float4*)&h0l[bq + j * 16][k4 * 4];
                acc[j] += rv.x * hv.x + rv.y * hv.y + rv.z * hv.z + rv.w * hv.w;
            }
        }
        __syncthreads();
    }
    float extra = ldsc(rb, hb + hl, f32) + ldsc(bb, hb + hl, f32);
    float* outz = rt + (size_t)z * 65536;
#pragma unroll
    for (int j = 0; j < 4; ++j)
        outz[(size_t)(bq + j * 16) * 1024 + hb + hl] = acc[j] + extra;
}

// ---------------- main fused GEMM v3: 8-wave phased pipeline ----------------
// Tile 256 m' x 64 h x 3 gates, BK=64, 512 threads (8 waves: 4m x 2n).
// LDS: 2 buffers x (A 32KB + 3x B 8KB) = 114688 B. 1 block/CU.
__global__ __launch_bounds__(512, 2) void lstm_main3(
    const void* __restrict__ x,                  // dtype detect only
    const void* __restrict__ c0,
    const unsigned short* __restrict__ xb,       // [64][512][1024] bf16 (native layout)
    const unsigned short* __restrict__ wb,       // [3][1024][1024] bf16
    const float* __restrict__ rt,
    void* __restrict__ dout)
{
    __shared__ __align__(16) unsigned char smem[114688];

    const int f32 = detect_f32(x);
    const int tid  = threadIdx.x;
    const int lane = tid & 63;
    const int w    = tid >> 6;      // 0..7
    const int wm   = w >> 1;        // 0..3
    const int wn   = w & 1;         // 0..1
    const int col  = lane & 15;
    const int quad = lane >> 4;

    // XCD-pinning swizzle: grid (16,128); XCD owns h-pair {2x,2x+1}, sweeps m-tiles.
    const int L    = blockIdx.x + (blockIdx.y << 4);
    const int xcd  = L & 7;
    const int s    = L >> 3;
    const int hblk = (xcd << 1) | (s & 1);   // 0..15
    const int mblk = s >> 1;                 // 0..127
    const int m0   = mblk << 8;
    const int h0t  = hblk << 6;

    // ---- staging descriptors (16B chunks, LDS linear, global pre-swizzled) ----
    // A: 2048 chunks -> 4/thread; row = ci>>3 (0..255), kc = ci&7.
    int cAd[4]; size_t gA[4];
#pragma unroll
    for (int i = 0; i < 4; ++i) {
        const int ci = tid + (i << 9);
        const int row = ci >> 3, kc = ci & 7;
        const int mg = m0 + row;
        const int xrow = ((mg & 63) << 9) + (mg >> 6);   // m' -> (b,t) native row
        cAd[i] = ci << 4;
        gA[i] = ((size_t)xrow << 10) + (size_t)((kc ^ (row & 7)) << 3);
    }
    // B (per gate): 512 chunks -> 1/thread.
    const int brow = tid >> 3, bkc = tid & 7;
    const int cBd  = tid << 4;
    const size_t gB = ((size_t)(h0t + brow) << 10) + (size_t)((bkc ^ (brow & 7)) << 3);

    // fragment read bases: rows of 128 B; XOR bits 4-6 by (col&7)
    const int xbits = (col & 7) << 4;
    int aRow[4], bRow[2];
#pragma unroll
    for (int mi = 0; mi < 4; ++mi) aRow[mi] = (wm * 64 + mi * 16 + col) << 7;
#pragma unroll
    for (int ni = 0; ni < 2; ++ni) bRow[ni] = (wn * 32 + ni * 16 + col) << 7;

    const unsigned short* wf = wb;
    const unsigned short* wi = wb + 1048576;
    const unsigned short* wg = wb + 2097152;

    f32x4 aF[4][2], aI[4][2], aG[4][2];
#pragma unroll
    for (int mi = 0; mi < 4; ++mi)
#pragma unroll
        for (int ni = 0; ni < 2; ++ni) {
            aF[mi][ni] = (f32x4)0.f; aI[mi][ni] = (f32x4)0.f; aG[mi][ni] = (f32x4)0.f;
        }

    // ---- prologue: stage tile 0 into buf0, drain, sync ----
#pragma unroll
    for (int i = 0; i < 4; ++i) gl_lds16(xb + gA[i], smem + cAd[i]);
    gl_lds16(wf + gB, smem + 32768 + cBd);
    gl_lds16(wi + gB, smem + 40960 + cBd);
    gl_lds16(wg + gB, smem + 49152 + cBd);
    asm volatile("s_waitcnt vmcnt(0)" ::: "memory");
    __builtin_amdgcn_s_barrier();

    int cur = 0;
    for (int kt = 0; kt < 16; ++kt) {
        const int nb = cur ^ 1;
        const unsigned cbase = (unsigned)cur * 57344u;
        const unsigned nbase = (unsigned)nb * 57344u;
        const size_t k0n = (size_t)(((kt + 1) & 15) << 6);   // wraps: last iter refetches tile0 (unread)

        s16x8 av[2][4];

        // ======== PHASE 0: gate F (A reads + F reads; stage A for kt+1) ========
        {
            s16x8 bv[2][2];
#pragma unroll
            for (int kh = 0; kh < 2; ++kh) {
                const int cb = ((kh << 6) | (quad << 4)) ^ xbits;
#pragma unroll
                for (int mi = 0; mi < 4; ++mi)
                    av[kh][mi] = *(const s16x8*)(smem + cbase + aRow[mi] + cb);
#pragma unroll
                for (int ni = 0; ni < 2; ++ni)
                    bv[kh][ni] = *(const s16x8*)(smem + cbase + 32768 + bRow[ni] + cb);
            }
#pragma unroll
            for (int i = 0; i < 4; ++i) gl_lds16(xb + gA[i] + k0n, smem + nbase + cAd[i]);
            gl_lds16(wf + gB + k0n, smem + nbase + 32768 + cBd);
            __builtin_amdgcn_s_barrier();
            __builtin_amdgcn_s_setprio(1);
#pragma unroll
            for (int kh = 0; kh < 2; ++kh)
#pragma unroll
                for (int mi = 0; mi < 4; ++mi)
#pragma unroll
                    for (int ni = 0; ni < 2; ++ni)
                        aF[mi][ni] = __builtin_amdgcn_mfma_f32_16x16x32_bf16(av[kh][mi], bv[kh][ni], aF[mi][ni], 0, 0, 0);
            __builtin_amdgcn_s_setprio(0);
            __builtin_amdgcn_s_barrier();
        }

        // ======== PHASE 1: gate I (stage Bi for kt+1) ========
        {
            s16x8 bv[2][2];
#pragma unroll
            for (int kh = 0; kh < 2; ++kh) {
                const int cb = ((kh << 6) | (quad << 4)) ^ xbits;
#pragma unroll
                for (int ni = 0; ni < 2; ++ni)
                    bv[kh][ni] = *(const s16x8*)(smem + cbase + 40960 + bRow[ni] + cb);
            }
            gl_lds16(wi + gB + k0n, smem + nbase + 40960 + cBd);
            __builtin_amdgcn_s_barrier();
            __builtin_amdgcn_s_setprio(1);
#pragma unroll
            for (int kh = 0; kh < 2; ++kh)
#pragma unroll
                for (int mi = 0; mi < 4; ++mi)
#pragma unroll
                    for (int ni = 0; ni < 2; ++ni)
                        aI[mi][ni] = __builtin_amdgcn_mfma_f32_16x16x32_bf16(av[kh][mi], bv[kh][ni], aI[mi][ni], 0, 0, 0);
            __builtin_amdgcn_s_setprio(0);
            __builtin_amdgcn_s_barrier();
        }

        // ======== PHASE 2: gate G (stage Bg for kt+1; vmcnt+barrier closes kt) ========
        {
            s16x8 bv[2][2];
#pragma unroll
            for (int kh = 0; kh < 2; ++kh) {
                const int cb = ((kh << 6) | (quad << 4)) ^ xbits;
#pragma unroll
                for (int ni = 0; ni < 2; ++ni)
                    bv[kh][ni] = *(const s16x8*)(smem + cbase + 49152 + bRow[ni] + cb);
            }
            gl_lds16(wg + gB + k0n, smem + nbase + 49152 + cBd);
            __builtin_amdgcn_s_barrier();
            __builtin_amdgcn_s_setprio(1);
#pragma unroll
            for (int kh = 0; kh < 2; ++kh)
#pragma unroll
                for (int mi = 0; mi < 4; ++mi)
#pragma unroll
                    for (int ni = 0; ni < 2; ++ni)
                        aG[mi][ni] = __builtin_amdgcn_mfma_f32_16x16x32_bf16(av[kh][mi], bv[kh][ni], aG[mi][ni], 0, 0, 0);
            __builtin_amdgcn_s_setprio(0);
            // kt+1 loads were issued >= 1-2 phases ago -> near-free drain
            asm volatile("s_waitcnt vmcnt(0)" ::: "memory");
            __builtin_amdgcn_s_barrier();
        }
        cur = nb;
    }

    // ---- epilogue ----
    const float* rtF = rt;
    const float* rtI = rt + 65536;
    const float* rtG = rt + 131072;
    unsigned short* outHb = (unsigned short*)dout;
    unsigned short* outHlb = outHb + 33554432;
    unsigned short* outClb = outHlb + 65536;
    float* outHf = (float*)dout;
    float* outHlf = outHf + 33554432;
    float* outClf = outHlf + 65536;

#pragma unroll
    for (int mi = 0; mi < 4; ++mi) {
#pragma unroll
        for (int ni = 0; ni < 2; ++ni) {
            const int hl = wn * 32 + ni * 16 + col;     // 0..63
            const int h  = h0t + hl;
            const int mbase = wm * 64 + mi * 16 + quad * 4;   // 0..255
            s16x4 packb;
            float4 packf;
#pragma unroll
            for (int r = 0; r < 4; ++r) {
                const int mg = m0 + mbase + r;
                const int b  = mg & 63;
                const int idx = b * 1024 + h;
                float pf = aF[mi][ni][r] + rtF[idx];
                float pi = aI[mi][ni][r] + rtI[idx];
                float pg = aG[mi][ni][r] + rtG[idx];
                float fv = sigm_(pf);
                float iv = sigm_(pi);
                float gv = tanh_(pg);
                float cv = fv * ldsc(c0, idx, f32) + iv * gv;
                float hv = tanh_(cv);
                if (r == 0) { packf.x = hv; } else if (r == 1) { packf.y = hv; }
                else if (r == 2) { packf.z = hv; } else { packf.w = hv; }
                packb[r] = (short)f2bf(hv);
                if ((mg >> 6) == 511) {          // t == T-1
                    if (f32) { outHlf[idx] = hv; outClf[idx] = cv; }
                    else     { outHlb[idx] = f2bf(hv); outClb[idx] = f2bf(cv); }
                }
            }
            if (f32) {
                float* ldsTf = (float*)(smem + (size_t)hl * 1040);   // 256*4+16 pad
                *(float4*)(ldsTf + mbase) = packf;
            } else {
                *(s16x4*)(smem + (size_t)hl * 528 + mbase * 2) = packb;   // 256*2+16 pad
            }
        }
    }
    __syncthreads();

    const int hl = tid >> 3;                     // 0..63
    const int ch = tid & 7;                      // 8 chunks of 32 m'
    if (f32) {
        float* obase = outHf + (size_t)(h0t + hl) * 32768 + m0 + ch * 32;
        const unsigned char* trow = smem + (size_t)hl * 1040 + ch * 128;
#pragma unroll
        for (int j = 0; j < 8; ++j)
            *(float4*)(obase + j * 4) = *(const float4*)(trow + j * 16);
    } else {
        unsigned short* obase = outHb + (size_t)(h0t + hl) * 32768 + m0 + ch * 32;
        const unsigned char* trow = smem + (size_t)hl * 528 + ch * 64;
#pragma unroll
        for (int j = 0; j < 4; ++j)
            *(s16x8*)(obase + j * 8) = *(const s16x8*)(trow + j * 16);
    }
}

// ================= v1 fallback (workspace too small) =================
static __device__ __forceinline__ void stage8(const void* base, size_t eoff, short* dst, int f32) {
    if (f32) {
        const float* s = (const float*)base + eoff;
        float4 u0 = *(const float4*)s;
        float4 u1 = *(const float4*)(s + 4);
        s16x8 v;
        v[0] = (short)f2bf(u0.x); v[1] = (short)f2bf(u0.y);
        v[2] = (short)f2bf(u0.z); v[3] = (short)f2bf(u0.w);
        v[4] = (short)f2bf(u1.x); v[5] = (short)f2bf(u1.y);
        v[6] = (short)f2bf(u1.z); v[7] = (short)f2bf(u1.w);
        *(s16x8*)dst = v;
    } else {
        *(s16x8*)dst = *(const s16x8*)((const unsigned short*)base + eoff);
    }
}

__global__ __launch_bounds__(256) void rprep_kernel(
    const void* __restrict__ xdet,
    const void* __restrict__ h0,
    const void* __restrict__ Rf, const void* __restrict__ rbf, const void* __restrict__ bf_,
    const void* __restrict__ Ri, const void* __restrict__ rbi, const void* __restrict__ bi_,
    const void* __restrict__ Rg, const void* __restrict__ rbg, const void* __restrict__ bg_,
    float* __restrict__ rt)
{
    const int f32 = detect_f32(xdet);
    __shared__ float h0f[8][1024];
    const int tid = threadIdx.x;
    const int b0 = blockIdx.y * 8;
    const int z  = blockIdx.z;
    for (int idx = tid; idx < 8 * 1024; idx += 256) {
        int r = idx >> 10, k = idx & 1023;
        h0f[r][k] = ldsc(h0, (b0 + r) * 1024 + k, f32);
    }
    __syncthreads();
    const void* R  = (z == 0) ? Rf  : (z == 1) ? Ri  : Rg;
    const void* rb = (z == 0) ? rbf : (z == 1) ? rbi : rbg;
    const void* bb = (z == 0) ? bf_ : (z == 1) ? bi_ : bg_;
    const int h = blockIdx.x * 256 + tid;
    float acc[8];
#pragma unroll
    for (int i = 0; i < 8; ++i) acc[i] = 0.f;
    for (int k0 = 0; k0 < 1024; k0 += 8) {
        float rf[8];
        if (f32) {
            const float* Rrow = (const float*)R + (size_t)h * 1024;
            float4 a = *(const float4*)(Rrow + k0);
            float4 b = *(const float4*)(Rrow + k0 + 4);
            rf[0] = a.x; rf[1] = a.y; rf[2] = a.z; rf[3] = a.w;
            rf[4] = b.x; rf[5] = b.y; rf[6] = b.z; rf[7] = b.w;
        } else {
            const unsigned short* Rrow = (const unsigned short*)R + (size_t)h * 1024;
            s16x8 rv = *(const s16x8*)(Rrow + k0);
#pragma unroll
            for (int j = 0; j < 8; ++j) rf[j] = bf2f((unsigned short)rv[j]);
        }
#pragma unroll
        for (int b = 0; b < 8; ++b) {
            float4 u0 = *(const float4*)&h0f[b][k0];
            float4 u1 = *(const float4*)&h0f[b][k0 + 4];
            acc[b] += rf[0] * u0.x + rf[1] * u0.y + rf[2] * u0.z + rf[3] * u0.w
                    + rf[4] * u1.x + rf[5] * u1.y + rf[6] * u1.z + rf[7] * u1.w;
        }
    }
    float extra = ldsc(rb, h, f32) + ldsc(bb, h, f32);
    float* outz = rt + (size_t)z * 65536;
#pragma unroll
    for (int b = 0; b < 8; ++b) outz[(b0 + b) * 1024 + h] = acc[b] + extra;
}

__global__ __launch_bounds__(256, 2) void lstm_main(
    const void* __restrict__ x,
    const void* __restrict__ c0,
    const void* __restrict__ Wf,
    const void* __restrict__ Wi,
    const void* __restrict__ Wg,
    const float* __restrict__ rt,
    void* __restrict__ dout)
{
    __shared__ __align__(16) unsigned char smem[33792];
    short* smA  = (short*)smem;
    short* smBf = (short*)(smem + 8192);
    short* smBi = (short*)(smem + 12288);
    short* smBg = (short*)(smem + 16384);

    const int f32 = detect_f32(x);
    const int tid  = threadIdx.x;
    const int lane = tid & 63;
    const int w    = tid >> 6;
    const int wm   = w >> 1;
    const int wn   = w & 1;
    const int col  = lane & 15;
    const int quad = lane >> 4;

    const int m0  = blockIdx.y * 128;
    const int h0t = blockIdx.x * 64;

    const int cA0 = tid, cA1 = tid + 256;
    const int mgA0 = m0 + (cA0 >> 2), mgA1 = m0 + (cA1 >> 2);
    size_t aoff0 = (size_t)((mgA0 & 63) * 512 + (mgA0 >> 6)) * 1024 + (cA0 & 3) * 8;
    size_t aoff1 = (size_t)((mgA1 & 63) * 512 + (mgA1 >> 6)) * 1024 + (cA1 & 3) * 8;
    size_t boff = (size_t)(h0t + (tid >> 2)) * 1024 + (tid & 3) * 8;
    short* dA0 = smA  + cA0 * 8;
    short* dA1 = smA  + cA1 * 8;
    short* dBf = smBf + tid * 8;
    short* dBi = smBi + tid * 8;
    short* dBg = smBg + tid * 8;

    const short* aBase  = smA  + (wm * 64 + col) * 32 + quad * 8;
    const short* bfBase = smBf + (wn * 32 + col) * 32 + quad * 8;
    const short* biBase = smBi + (wn * 32 + col) * 32 + quad * 8;
    const short* bgBase = smBg + (wn * 32 + col) * 32 + quad * 8;

    f32x4 aF[4][2], aI[4][2], aG[4][2];
#pragma unroll
    for (int mi = 0; mi < 4; ++mi)
#pragma unroll
        for (int ni = 0; ni < 2; ++ni) {
            aF[mi][ni] = (f32x4)0.f; aI[mi][ni] = (f32x4)0.f; aG[mi][ni] = (f32x4)0.f;
        }

    for (int kt = 0; kt < 32; ++kt) {
        const size_t ko = (size_t)kt * 32;
        stage8(x,  aoff0 + ko, dA0, f32);
        stage8(x,  aoff1 + ko, dA1, f32);
        stage8(Wf, boff  + ko, dBf, f32);
        stage8(Wi, boff  + ko, dBi, f32);
        stage8(Wg, boff  + ko, dBg, f32);
        __syncthreads();

        s16x8 av[4], bfv[2], biv[2], bgv[2];
#pragma unroll
        for (int mi = 0; mi < 4; ++mi) av[mi] = *(const s16x8*)(aBase + mi * 512);
#pragma unroll
        for (int ni = 0; ni < 2; ++ni) {
            bfv[ni] = *(const s16x8*)(bfBase + ni * 512);
            biv[ni] = *(const s16x8*)(biBase + ni * 512);
            bgv[ni] = *(const s16x8*)(bgBase + ni * 512);
        }
#pragma unroll
        for (int mi = 0; mi < 4; ++mi)
#pragma unroll
            for (int ni = 0; ni < 2; ++ni) {
                aF[mi][ni] = __builtin_amdgcn_mfma_f32_16x16x32_bf16(av[mi], bfv[ni], aF[mi][ni], 0, 0, 0);
                aI[mi][ni] = __builtin_amdgcn_mfma_f32_16x16x32_bf16(av[mi], biv[ni], aI[mi][ni], 0, 0, 0);
                aG[mi][ni] = __builtin_amdgcn_mfma_f32_16x16x32_bf16(av[mi], bgv[ni], aG[mi][ni], 0, 0, 0);
            }
        __syncthreads();
    }

    const float* rtF = rt;
    const float* rtI = rt + 65536;
    const float* rtG = rt + 131072;
    unsigned short* outHb = (unsigned short*)dout;
    unsigned short* outHlb = outHb + 33554432;
    unsigned short* outClb = outHlb + 65536;
    float* outHf = (float*)dout;
    float* outHlf = outHf + 33554432;
    float* outClf = outHlf + 65536;

#pragma unroll
    for (int mi = 0; mi < 4; ++mi) {
#pragma unroll
        for (int ni = 0; ni < 2; ++ni) {
            const int hl = wn * 32 + ni * 16 + col;
            const int h  = h0t + hl;
            const int mbase = wm * 64 + mi * 16 + quad * 4;
            s16x4 packb;
            float4 packf;
#pragma unroll
            for (int r = 0; r < 4; ++r) {
                const int mg = m0 + mbase + r;
                const int b  = mg & 63;
                const int idx = b * 1024 + h;
                float pf = aF[mi][ni][r] + rtF[idx];
                float pi = aI[mi][ni][r] + rtI[idx];
                float pg = aG[mi][ni][r] + rtG[idx];
                float fv = sigm_(pf);
                float iv = sigm_(pi);
                float gv = tanh_(pg);
                float cv = fv * ldsc(c0, idx, f32) + iv * gv;
                float hv = tanh_(cv);
                if (r == 0) { packf.x = hv; } else if (r == 1) { packf.y = hv; }
                else if (r == 2) { packf.z = hv; } else { packf.w = hv; }
                packb[r] = (short)f2bf(hv);
                if ((mg >> 6) == 511) {
                    if (f32) { outHlf[idx] = hv; outClf[idx] = cv; }
                    else     { outHlb[idx] = f2bf(hv); outClb[idx] = f2bf(cv); }
                }
            }
            if (f32) {
                float* ldsTf = (float*)(smem + (size_t)hl * 528);
                *(float4*)(ldsTf + mbase) = packf;
            } else {
                *(s16x4*)(smem + (size_t)hl * 272 + mbase * 2) = packb;
            }
        }
    }
    __syncthreads();

    const int hl = tid >> 2;
    const int ch = tid & 3;
    if (f32) {
        float* obase = outHf + (size_t)(h0t + hl) * 32768 + m0 + ch * 32;
        const unsigned char* trow = smem + (size_t)hl * 528 + ch * 128;
#pragma unroll
        for (int j = 0; j < 8; ++j)
            *(float4*)(obase + j * 4) = *(const float4*)(trow + j * 16);
    } else {
        unsigned short* obase = outHb + (size_t)(h0t + hl) * 32768 + m0 + ch * 32;
        const unsigned char* trow = smem + (size_t)hl * 272 + ch * 64;
#pragma unroll
        for (int j = 0; j < 4; ++j)
            *(s16x8*)(obase + j * 8) = *(const s16x8*)(trow + j * 16);
    }
}

extern "C" void kernel_launch(void* const* d_in, const int* in_sizes, int n_in,
                              void* d_out, int out_size, void* d_ws, size_t ws_size,
                              hipStream_t stream) {
    (void)in_sizes; (void)n_in; (void)out_size;
    const void* x   = d_in[0];
    const void* h0  = d_in[1];
    const void* c0  = d_in[2];
    const void* Wf  = d_in[3];
    const void* bf_ = d_in[4];
    const void* Rf  = d_in[5];
    const void* rbf = d_in[6];
    const void* Wi  = d_in[7];
    const void* bi_ = d_in[8];
    const void* Ri  = d_in[9];
    const void* rbi = d_in[10];
    const void* Wg  = d_in[11];
    const void* bg_ = d_in[12];
    const void* Rg  = d_in[13];
    const void* rbg = d_in[14];
    // d_in[15..18] = Wo, bo, Ro, rbo — dead in the reference, never read.

    // ws layout: xb bf16 [32768][1024] (64 MB) | wb bf16 [3][1024][1024] (6 MB) | rt fp32 (768 KB)
    const size_t NEED = 67108864ull + 6291456ull + 786432ull;
    if (ws_size >= NEED) {
        unsigned short* xb = (unsigned short*)d_ws;
        unsigned short* wbp = xb + 33554432ull;
        float* rt = (float*)(wbp + 3145728ull);
        prep_fused<<<dim3(18112), 256, 0, stream>>>(x, Wf, Wi, Wg, h0,
                                                    Rf, rbf, bf_, Ri, rbi, bi_, Rg, rbg, bg_,
                                                    xb, wbp, rt);
        lstm_main3<<<dim3(16, 128), 512, 0, stream>>>(x, c0, xb, wbp, rt, d_out);
    } else {
        float* rt = (float*)d_ws;
        rprep_kernel<<<dim3(4, 8, 3), 256, 0, stream>>>(x, h0, Rf, rbf, bf_, Ri, rbi, bi_, Rg, rbg, bg_, rt);
        lstm_main<<<dim3(16, 256), 256, 0, stream>>>(x, c0, Wf, Wi, Wg, rt, d_out);
    }
}

// Round 4
// 620.368 us; speedup vs baseline: 1.0402x; 1.0402x over previous
//
#include <hip/hip_runtime.h>
#include <cstdint>

// Problem: B=64, T=512, I=K=1024, H=1024.
// Reference collapses to: rtot_z = h0@R_z^T + rb_z + b_z  (z in {f,i,g}; o-gate dead)
//   gate_z[m',h] = x_perm[m'] . W_z^T + rtot_z[b,h]   with m' = t*64 + b
//   c = sig(f)*c0 + sig(i)*tanh(g); hidden[h, m'] = tanh(c); last-t -> h_last, c_last.
//
// v5 this round: revert v3's 3-phase (regressed: full-drain per kt + 1 blk/CU +
// 6 barriers/kt). lstm_main4 = main2 structure (128m x 64h, 4 waves, BK=64,
// proven 745 TF) + T3 "minimum 2-phase": double-buffered LDS (2x40KB = 80KB,
// exactly 2 blocks/CU), stage kt+1 BEFORE computing kt, one raw s_barrier per
// kt, vmcnt(0) drain placed AFTER the 48-MFMA compute (latency hidden).
// prep_fused unchanged. ~220us/iter is fixed harness reset overhead.

typedef short s16x8 __attribute__((ext_vector_type(8)));
typedef short s16x4 __attribute__((ext_vector_type(4)));
typedef float f32x4 __attribute__((ext_vector_type(4)));

static __device__ __forceinline__ float bf2f(unsigned short u) {
    union { unsigned int i; float f; } v; v.i = ((unsigned int)u) << 16; return v.f;
}
static __device__ __forceinline__ unsigned short f2bf(float f) {
    union { float f; unsigned int i; } v; v.f = f;
    unsigned int u = v.i;
    return (unsigned short)((u + 0x7fffu + ((u >> 16) & 1u)) >> 16);
}
static __device__ __forceinline__ float sigm_(float x) { return 1.0f / (1.0f + __expf(-x)); }
static __device__ __forceinline__ float tanh_(float x) { return 1.0f - 2.0f / (1.0f + __expf(2.0f * x)); }

// Detect fp32 vs bf16 storage (wave-uniform, deterministic).
static __device__ __forceinline__ int detect_f32(const void* x) {
    const unsigned int* u = (const unsigned int*)x;
    int c = 0;
#pragma unroll
    for (int i = 0; i < 16; ++i) {
        unsigned int e = (u[i] >> 23) & 255u;
        c += (e >= 100u && e <= 140u) ? 1 : 0;
    }
    return c >= 8;
}

static __device__ __forceinline__ float ldsc(const void* p, int i, int f32) {
    return f32 ? ((const float*)p)[i] : bf2f(((const unsigned short*)p)[i]);
}

static __device__ __forceinline__ float4 load4f(const void* p, size_t eoff, int f32) {
    if (f32) return *(const float4*)((const float*)p + eoff);
    s16x4 v = *(const s16x4*)((const unsigned short*)p + eoff);
    return make_float4(bf2f((unsigned short)v[0]), bf2f((unsigned short)v[1]),
                       bf2f((unsigned short)v[2]), bf2f((unsigned short)v[3]));
}

// 16B direct global->LDS. LDS dest linear in lane order (uniform base + lane*16).
static __device__ __forceinline__ void gl_lds16(const void* g, void* l) {
    __builtin_amdgcn_global_load_lds(
        (const __attribute__((address_space(1))) unsigned int*)g,
        (__attribute__((address_space(3))) unsigned int*)l, 16, 0, 0);
}

// ---------------- fused prep: linear bf16 convert of x,W  +  rprep ----------------
__global__ __launch_bounds__(256) void prep_fused(
    const void* __restrict__ x,
    const void* __restrict__ Wf, const void* __restrict__ Wi, const void* __restrict__ Wg,
    const void* __restrict__ h0,
    const void* __restrict__ Rf, const void* __restrict__ rbf, const void* __restrict__ bf_,
    const void* __restrict__ Ri, const void* __restrict__ rbi, const void* __restrict__ bi_,
    const void* __restrict__ Rg, const void* __restrict__ rbg, const void* __restrict__ bg_,
    unsigned short* __restrict__ xb, unsigned short* __restrict__ wb,
    float* __restrict__ rt)
{
    __shared__ float h0l[64][132];
    __shared__ float Rl[16][132];
    const int f32 = detect_f32(x);
    const int tid = threadIdx.x;
    const int bid = blockIdx.x;

    if (bid < 17920) {
        const int r = bid * 2 + (tid >> 7);
        const int c = (tid & 127) << 3;
        const void* src;
        size_t soff;
        unsigned short* dst;
        if (r < 32768) {
            src = x;
            soff = ((size_t)r << 10) + c;
            dst = xb + soff;
        } else {
            const int wr = r - 32768;
            const int g = wr >> 10;
            src = (g == 0) ? Wf : (g == 1) ? Wi : Wg;
            soff = ((size_t)(wr & 1023) << 10) + c;
            dst = wb + ((size_t)wr << 10) + c;
        }
        if (f32) {
            const float* s = (const float*)src + soff;
            float4 u0 = *(const float4*)s;
            float4 u1 = *(const float4*)(s + 4);
            s16x8 v;
            v[0] = (short)f2bf(u0.x); v[1] = (short)f2bf(u0.y);
            v[2] = (short)f2bf(u0.z); v[3] = (short)f2bf(u0.w);
            v[4] = (short)f2bf(u1.x); v[5] = (short)f2bf(u1.y);
            v[6] = (short)f2bf(u1.z); v[7] = (short)f2bf(u1.w);
            *(s16x8*)dst = v;
        } else {
            *(s16x8*)dst = *(const s16x8*)((const unsigned short*)src + soff);
        }
        return;
    }

    const int pb = bid - 17920;
    const int z  = pb >> 6;
    const int hb = (pb & 63) * 16;
    const void* R  = (z == 0) ? Rf  : (z == 1) ? Ri  : Rg;
    const void* rb = (z == 0) ? rbf : (z == 1) ? rbi : rbg;
    const void* bb = (z == 0) ? bf_ : (z == 1) ? bi_ : bg_;
    const int hl = tid >> 4;
    const int bq = tid & 15;
    float acc[4] = {0.f, 0.f, 0.f, 0.f};

    for (int k0 = 0; k0 < 1024; k0 += 128) {
#pragma unroll
        for (int i = 0; i < 8; ++i) {
            int lin = i * 256 + tid;
            int r = lin >> 5, c4 = lin & 31;
            *(float4*)&h0l[r][c4 * 4] = load4f(h0, (size_t)r * 1024 + k0 + c4 * 4, f32);
        }
#pragma unroll
        for (int i = 0; i < 2; ++i) {
            int lin = i * 256 + tid;
            int r = lin >> 5, c4 = lin & 31;
            *(float4*)&Rl[r][c4 * 4] = load4f(R, (size_t)(hb + r) * 1024 + k0 + c4 * 4, f32);
        }
        __syncthreads();
#pragma unroll 8
        for (int k4 = 0; k4 < 32; ++k4) {
            float4 rv = *(const float4*)&Rl[hl][k4 * 4];
#pragma unroll
            for (int j = 0; j < 4; ++j) {
                float4 hv = *(const float4*)&h0l[bq + j * 16][k4 * 4];
                acc[j] += rv.x * hv.x + rv.y * hv.y + rv.z * hv.z + rv.w * hv.w;
            }
        }
        __syncthreads();
    }
    float extra = ldsc(rb, hb + hl, f32) + ldsc(bb, hb + hl, f32);
    float* outz = rt + (size_t)z * 65536;
#pragma unroll
    for (int j = 0; j < 4; ++j)
        outz[(size_t)(bq + j * 16) * 1024 + hb + hl] = acc[j] + extra;
}

// ---------------- main fused GEMM v5: main2 + 2-phase double-buffer ----------------
// Tile 128 m' x 64 h x 3 gates, BK=64, 4 waves 2x2, 256 threads.
// LDS: 2 buffers x (A 16KB + 3x B 8KB) = 81920 B -> exactly 2 blocks/CU.
// Per kt: issue 10 gl_lds16 for kt+1 into other buffer -> compute kt (48 MFMA)
// -> vmcnt(0) (latency hidden behind compute) -> one raw s_barrier.
__global__ __launch_bounds__(256, 2) void lstm_main4(
    const void* __restrict__ x,                  // dtype detect only
    const void* __restrict__ c0,
    const unsigned short* __restrict__ xb,       // [64][512][1024] bf16 (native layout)
    const unsigned short* __restrict__ wb,       // [3][1024][1024] bf16
    const float* __restrict__ rt,
    void* __restrict__ dout)
{
    __shared__ __align__(16) unsigned char smem[81920];

    const int f32 = detect_f32(x);
    const int tid  = threadIdx.x;
    const int lane = tid & 63;
    const int w    = tid >> 6;
    const int wm   = w >> 1;
    const int wn   = w & 1;
    const int col  = lane & 15;
    const int quad = lane >> 4;

    // XCD-pinning block swizzle: XCD = L%8 owns h-tiles {2x,2x+1}; m-tiles sweep.
    const int L    = blockIdx.x + (blockIdx.y << 4);   // grid (16, 256)
    const int xcd  = L & 7;
    const int s    = L >> 3;
    const int hblk = (xcd << 1) | (s & 1);
    const int mblk = s >> 1;
    const int m0   = mblk << 7;
    const int h0t  = hblk << 6;

    // staging descriptors: 16B chunks, LDS linear, global source pre-swizzled.
    // A source row in xb's native layout: m' = m0+row -> xrow = (m'&63)*512 + (m'>>6).
    int   cA[4]; size_t gA[4];
#pragma unroll
    for (int i = 0; i < 4; ++i) {
        const int ci = tid + (i << 8);
        const int row = ci >> 3, kc = ci & 7;
        const int mg = m0 + row;
        const int xrow = ((mg & 63) << 9) + (mg >> 6);
        cA[i] = ci << 4;
        gA[i] = ((size_t)xrow << 10) + (size_t)((kc ^ (row & 7)) << 3);
    }
    int   cB[2]; size_t gB[2];
#pragma unroll
    for (int i = 0; i < 2; ++i) {
        const int ci = tid + (i << 8);
        const int row = ci >> 3, kc = ci & 7;
        cB[i] = ci << 4;
        gB[i] = ((size_t)(h0t + row) << 10) + (size_t)((kc ^ (row & 7)) << 3);
    }

    // fragment read bases (bytes); rows of 128 B; XOR bits 4-6 by (col&7)
    const int xbits = (col & 7) << 4;
    int aRow[4], bRow[2];
#pragma unroll
    for (int mi = 0; mi < 4; ++mi) aRow[mi] = (wm * 64 + mi * 16 + col) << 7;
#pragma unroll
    for (int ni = 0; ni < 2; ++ni) bRow[ni] = (wn * 32 + ni * 16 + col) << 7;

    const unsigned short* wf = wb;
    const unsigned short* wi = wb + 1048576;
    const unsigned short* wg = wb + 2097152;

    f32x4 aF[4][2], aI[4][2], aG[4][2];
#pragma unroll
    for (int mi = 0; mi < 4; ++mi)
#pragma unroll
        for (int ni = 0; ni < 2; ++ni) {
            aF[mi][ni] = (f32x4)0.f; aI[mi][ni] = (f32x4)0.f; aG[mi][ni] = (f32x4)0.f;
        }

    // ---- prologue: stage tile 0 into buf0, drain, sync ----
#pragma unroll
    for (int i = 0; i < 4; ++i) gl_lds16(xb + gA[i], smem + cA[i]);
#pragma unroll
    for (int i = 0; i < 2; ++i) {
        gl_lds16(wf + gB[i], smem + 16384 + cB[i]);
        gl_lds16(wi + gB[i], smem + 24576 + cB[i]);
        gl_lds16(wg + gB[i], smem + 32768 + cB[i]);
    }
    asm volatile("s_waitcnt vmcnt(0)" ::: "memory");
    __builtin_amdgcn_s_barrier();

    unsigned cur = 0;                            // byte offset of current buffer
    for (int kt = 0; kt < 16; ++kt) {
        const unsigned nb0 = cur ^ 40960u;
        // ---- issue next-tile staging FIRST (latency hides under compute) ----
        if (kt < 15) {
            const size_t k0n = (size_t)(kt + 1) << 6;
#pragma unroll
            for (int i = 0; i < 4; ++i) gl_lds16(xb + gA[i] + k0n, smem + nb0 + cA[i]);
#pragma unroll
            for (int i = 0; i < 2; ++i) {
                gl_lds16(wf + gB[i] + k0n, smem + nb0 + 16384 + cB[i]);
                gl_lds16(wi + gB[i] + k0n, smem + nb0 + 24576 + cB[i]);
                gl_lds16(wg + gB[i] + k0n, smem + nb0 + 32768 + cB[i]);
            }
        }
        // ---- compute current tile ----
#pragma unroll
        for (int kh = 0; kh < 2; ++kh) {
            const int cb = (((kh << 6) | (quad << 4)) ^ xbits);
            s16x8 av[4], bfv[2], biv[2], bgv[2];
#pragma unroll
            for (int mi = 0; mi < 4; ++mi)
                av[mi] = *(const s16x8*)(smem + cur + aRow[mi] + cb);
#pragma unroll
            for (int ni = 0; ni < 2; ++ni) {
                bfv[ni] = *(const s16x8*)(smem + cur + 16384 + bRow[ni] + cb);
                biv[ni] = *(const s16x8*)(smem + cur + 24576 + bRow[ni] + cb);
                bgv[ni] = *(const s16x8*)(smem + cur + 32768 + bRow[ni] + cb);
            }
#pragma unroll
            for (int mi = 0; mi < 4; ++mi)
#pragma unroll
                for (int ni = 0; ni < 2; ++ni) {
                    aF[mi][ni] = __builtin_amdgcn_mfma_f32_16x16x32_bf16(av[mi], bfv[ni], aF[mi][ni], 0, 0, 0);
                    aI[mi][ni] = __builtin_amdgcn_mfma_f32_16x16x32_bf16(av[mi], biv[ni], aI[mi][ni], 0, 0, 0);
                    aG[mi][ni] = __builtin_amdgcn_mfma_f32_16x16x32_bf16(av[mi], bgv[ni], aG[mi][ni], 0, 0, 0);
                }
        }
        // ---- close kt: loads issued before compute are (mostly) landed ----
        asm volatile("s_waitcnt vmcnt(0)" ::: "memory");
        __builtin_amdgcn_s_barrier();
        cur = nb0;
    }

    // ---- epilogue (identical math to main2) ----
    const float* rtF = rt;
    const float* rtI = rt + 65536;
    const float* rtG = rt + 131072;
    unsigned short* outHb = (unsigned short*)dout;
    unsigned short* outHlb = outHb + 33554432;
    unsigned short* outClb = outHlb + 65536;
    float* outHf = (float*)dout;
    float* outHlf = outHf + 33554432;
    float* outClf = outHlf + 65536;

#pragma unroll
    for (int mi = 0; mi < 4; ++mi) {
#pragma unroll
        for (int ni = 0; ni < 2; ++ni) {
            const int hl = wn * 32 + ni * 16 + col;
            const int h  = h0t + hl;
            const int mbase = wm * 64 + mi * 16 + quad * 4;
            s16x4 packb;
            float4 packf;
#pragma unroll
            for (int r = 0; r < 4; ++r) {
                const int mg = m0 + mbase + r;
                const int b  = mg & 63;
                const int idx = b * 1024 + h;
                float pf = aF[mi][ni][r] + rtF[idx];
                float pi = aI[mi][ni][r] + rtI[idx];
                float pg = aG[mi][ni][r] + rtG[idx];
                float fv = sigm_(pf);
                float iv = sigm_(pi);
                float gv = tanh_(pg);
                float cv = fv * ldsc(c0, idx, f32) + iv * gv;
                float hv = tanh_(cv);
                if (r == 0) { packf.x = hv; } else if (r == 1) { packf.y = hv; }
                else if (r == 2) { packf.z = hv; } else { packf.w = hv; }
                packb[r] = (short)f2bf(hv);
                if ((mg >> 6) == 511) {          // t == T-1
                    if (f32) { outHlf[idx] = hv; outClf[idx] = cv; }
                    else     { outHlb[idx] = f2bf(hv); outClb[idx] = f2bf(cv); }
                }
            }
            if (f32) {
                float* ldsTf = (float*)(smem + (size_t)hl * 528);
                *(float4*)(ldsTf + mbase) = packf;
            } else {
                *(s16x4*)(smem + (size_t)hl * 272 + mbase * 2) = packb;
            }
        }
    }
    __syncthreads();

    const int hl = tid >> 2;
    const int ch = tid & 3;
    if (f32) {
        float* obase = outHf + (size_t)(h0t + hl) * 32768 + m0 + ch * 32;
        const unsigned char* trow = smem + (size_t)hl * 528 + ch * 128;
#pragma unroll
        for (int j = 0; j < 8; ++j)
            *(float4*)(obase + j * 4) = *(const float4*)(trow + j * 16);
    } else {
        unsigned short* obase = outHb + (size_t)(h0t + hl) * 32768 + m0 + ch * 32;
        const unsigned char* trow = smem + (size_t)hl * 272 + ch * 64;
#pragma unroll
        for (int j = 0; j < 4; ++j)
            *(s16x8*)(obase + j * 8) = *(const s16x8*)(trow + j * 16);
    }
}

// ================= v1 fallback (workspace too small) =================
static __device__ __forceinline__ void stage8(const void* base, size_t eoff, short* dst, int f32) {
    if (f32) {
        const float* s = (const float*)base + eoff;
        float4 u0 = *(const float4*)s;
        float4 u1 = *(const float4*)(s + 4);
        s16x8 v;
        v[0] = (short)f2bf(u0.x); v[1] = (short)f2bf(u0.y);
        v[2] = (short)f2bf(u0.z); v[3] = (short)f2bf(u0.w);
        v[4] = (short)f2bf(u1.x); v[5] = (short)f2bf(u1.y);
        v[6] = (short)f2bf(u1.z); v[7] = (short)f2bf(u1.w);
        *(s16x8*)dst = v;
    } else {
        *(s16x8*)dst = *(const s16x8*)((const unsigned short*)base + eoff);
    }
}

__global__ __launch_bounds__(256) void rprep_kernel(
    const void* __restrict__ xdet,
    const void* __restrict__ h0,
    const void* __restrict__ Rf, const void* __restrict__ rbf, const void* __restrict__ bf_,
    const void* __restrict__ Ri, const void* __restrict__ rbi, const void* __restrict__ bi_,
    const void* __restrict__ Rg, const void* __restrict__ rbg, const void* __restrict__ bg_,
    float* __restrict__ rt)
{
    const int f32 = detect_f32(xdet);
    __shared__ float h0f[8][1024];
    const int tid = threadIdx.x;
    const int b0 = blockIdx.y * 8;
    const int z  = blockIdx.z;
    for (int idx = tid; idx < 8 * 1024; idx += 256) {
        int r = idx >> 10, k = idx & 1023;
        h0f[r][k] = ldsc(h0, (b0 + r) * 1024 + k, f32);
    }
    __syncthreads();
    const void* R  = (z == 0) ? Rf  : (z == 1) ? Ri  : Rg;
    const void* rb = (z == 0) ? rbf : (z == 1) ? rbi : rbg;
    const void* bb = (z == 0) ? bf_ : (z == 1) ? bi_ : bg_;
    const int h = blockIdx.x * 256 + tid;
    float acc[8];
#pragma unroll
    for (int i = 0; i < 8; ++i) acc[i] = 0.f;
    for (int k0 = 0; k0 < 1024; k0 += 8) {
        float rf[8];
        if (f32) {
            const float* Rrow = (const float*)R + (size_t)h * 1024;
            float4 a = *(const float4*)(Rrow + k0);
            float4 b = *(const float4*)(Rrow + k0 + 4);
            rf[0] = a.x; rf[1] = a.y; rf[2] = a.z; rf[3] = a.w;
            rf[4] = b.x; rf[5] = b.y; rf[6] = b.z; rf[7] = b.w;
        } else {
            const unsigned short* Rrow = (const unsigned short*)R + (size_t)h * 1024;
            s16x8 rv = *(const s16x8*)(Rrow + k0);
#pragma unroll
            for (int j = 0; j < 8; ++j) rf[j] = bf2f((unsigned short)rv[j]);
        }
#pragma unroll
        for (int b = 0; b < 8; ++b) {
            float4 u0 = *(const float4*)&h0f[b][k0];
            float4 u1 = *(const float4*)&h0f[b][k0 + 4];
            acc[b] += rf[0] * u0.x + rf[1] * u0.y + rf[2] * u0.z + rf[3] * u0.w
                    + rf[4] * u1.x + rf[5] * u1.y + rf[6] * u1.z + rf[7] * u1.w;
        }
    }
    float extra = ldsc(rb, h, f32) + ldsc(bb, h, f32);
    float* outz = rt + (size_t)z * 65536;
#pragma unroll
    for (int b = 0; b < 8; ++b) outz[(b0 + b) * 1024 + h] = acc[b] + extra;
}

__global__ __launch_bounds__(256, 2) void lstm_main(
    const void* __restrict__ x,
    const void* __restrict__ c0,
    const void* __restrict__ Wf,
    const void* __restrict__ Wi,
    const void* __restrict__ Wg,
    const float* __restrict__ rt,
    void* __restrict__ dout)
{
    __shared__ __align__(16) unsigned char smem[33792];
    short* smA  = (short*)smem;
    short* smBf = (short*)(smem + 8192);
    short* smBi = (short*)(smem + 12288);
    short* smBg = (short*)(smem + 16384);

    const int f32 = detect_f32(x);
    const int tid  = threadIdx.x;
    const int lane = tid & 63;
    const int w    = tid >> 6;
    const int wm   = w >> 1;
    const int wn   = w & 1;
    const int col  = lane & 15;
    const int quad = lane >> 4;

    const int m0  = blockIdx.y * 128;
    const int h0t = blockIdx.x * 64;

    const int cA0 = tid, cA1 = tid + 256;
    const int mgA0 = m0 + (cA0 >> 2), mgA1 = m0 + (cA1 >> 2);
    size_t aoff0 = (size_t)((mgA0 & 63) * 512 + (mgA0 >> 6)) * 1024 + (cA0 & 3) * 8;
    size_t aoff1 = (size_t)((mgA1 & 63) * 512 + (mgA1 >> 6)) * 1024 + (cA1 & 3) * 8;
    size_t boff = (size_t)(h0t + (tid >> 2)) * 1024 + (tid & 3) * 8;
    short* dA0 = smA  + cA0 * 8;
    short* dA1 = smA  + cA1 * 8;
    short* dBf = smBf + tid * 8;
    short* dBi = smBi + tid * 8;
    short* dBg = smBg + tid * 8;

    const short* aBase  = smA  + (wm * 64 + col) * 32 + quad * 8;
    const short* bfBase = smBf + (wn * 32 + col) * 32 + quad * 8;
    const short* biBase = smBi + (wn * 32 + col) * 32 + quad * 8;
    const short* bgBase = smBg + (wn * 32 + col) * 32 + quad * 8;

    f32x4 aF[4][2], aI[4][2], aG[4][2];
#pragma unroll
    for (int mi = 0; mi < 4; ++mi)
#pragma unroll
        for (int ni = 0; ni < 2; ++ni) {
            aF[mi][ni] = (f32x4)0.f; aI[mi][ni] = (f32x4)0.f; aG[mi][ni] = (f32x4)0.f;
        }

    for (int kt = 0; kt < 32; ++kt) {
        const size_t ko = (size_t)kt * 32;
        stage8(x,  aoff0 + ko, dA0, f32);
        stage8(x,  aoff1 + ko, dA1, f32);
        stage8(Wf, boff  + ko, dBf, f32);
        stage8(Wi, boff  + ko, dBi, f32);
        stage8(Wg, boff  + ko, dBg, f32);
        __syncthreads();

        s16x8 av[4], bfv[2], biv[2], bgv[2];
#pragma unroll
        for (int mi = 0; mi < 4; ++mi) av[mi] = *(const s16x8*)(aBase + mi * 512);
#pragma unroll
        for (int ni = 0; ni < 2; ++ni) {
            bfv[ni] = *(const s16x8*)(bfBase + ni * 512);
            biv[ni] = *(const s16x8*)(biBase + ni * 512);
            bgv[ni] = *(const s16x8*)(bgBase + ni * 512);
        }
#pragma unroll
        for (int mi = 0; mi < 4; ++mi)
#pragma unroll
            for (int ni = 0; ni < 2; ++ni) {
                aF[mi][ni] = __builtin_amdgcn_mfma_f32_16x16x32_bf16(av[mi], bfv[ni], aF[mi][ni], 0, 0, 0);
                aI[mi][ni] = __builtin_amdgcn_mfma_f32_16x16x32_bf16(av[mi], biv[ni], aI[mi][ni], 0, 0, 0);
                aG[mi][ni] = __builtin_amdgcn_mfma_f32_16x16x32_bf16(av[mi], bgv[ni], aG[mi][ni], 0, 0, 0);
            }
        __syncthreads();
    }

    const float* rtF = rt;
    const float* rtI = rt + 65536;
    const float* rtG = rt + 131072;
    unsigned short* outHb = (unsigned short*)dout;
    unsigned short* outHlb = outHb + 33554432;
    unsigned short* outClb = outHlb + 65536;
    float* outHf = (float*)dout;
    float* outHlf = outHf + 33554432;
    float* outClf = outHlf + 65536;

#pragma unroll
    for (int mi = 0; mi < 4; ++mi) {
#pragma unroll
        for (int ni = 0; ni < 2; ++ni) {
            const int hl = wn * 32 + ni * 16 + col;
            const int h  = h0t + hl;
            const int mbase = wm * 64 + mi * 16 + quad * 4;
            s16x4 packb;
            float4 packf;
#pragma unroll
            for (int r = 0; r < 4; ++r) {
                const int mg = m0 + mbase + r;
                const int b  = mg & 63;
                const int idx = b * 1024 + h;
                float pf = aF[mi][ni][r] + rtF[idx];
                float pi = aI[mi][ni][r] + rtI[idx];
                float pg = aG[mi][ni][r] + rtG[idx];
                float fv = sigm_(pf);
                float iv = sigm_(pi);
                float gv = tanh_(pg);
                float cv = fv * ldsc(c0, idx, f32) + iv * gv;
                float hv = tanh_(cv);
                if (r == 0) { packf.x = hv; } else if (r == 1) { packf.y = hv; }
                else if (r == 2) { packf.z = hv; } else { packf.w = hv; }
                packb[r] = (short)f2bf(hv);
                if ((mg >> 6) == 511) {
                    if (f32) { outHlf[idx] = hv; outClf[idx] = cv; }
                    else     { outHlb[idx] = f2bf(hv); outClb[idx] = f2bf(cv); }
                }
            }
            if (f32) {
                float* ldsTf = (float*)(smem + (size_t)hl * 528);
                *(float4*)(ldsTf + mbase) = packf;
            } else {
                *(s16x4*)(smem + (size_t)hl * 272 + mbase * 2) = packb;
            }
        }
    }
    __syncthreads();

    const int hl = tid >> 2;
    const int ch = tid & 3;
    if (f32) {
        float* obase = outHf + (size_t)(h0t + hl) * 32768 + m0 + ch * 32;
        const unsigned char* trow = smem + (size_t)hl * 528 + ch * 128;
#pragma unroll
        for (int j = 0; j < 8; ++j)
            *(float4*)(obase + j * 4) = *(const float4*)(trow + j * 16);
    } else {
        unsigned short* obase = outHb + (size_t)(h0t + hl) * 32768 + m0 + ch * 32;
        const unsigned char* trow = smem + (size_t)hl * 272 + ch * 64;
#pragma unroll
        for (int j = 0; j < 4; ++j)
            *(s16x8*)(obase + j * 8) = *(const s16x8*)(trow + j * 16);
    }
}

extern "C" void kernel_launch(void* const* d_in, const int* in_sizes, int n_in,
                              void* d_out, int out_size, void* d_ws, size_t ws_size,
                              hipStream_t stream) {
    (void)in_sizes; (void)n_in; (void)out_size;
    const void* x   = d_in[0];
    const void* h0  = d_in[1];
    const void* c0  = d_in[2];
    const void* Wf  = d_in[3];
    const void* bf_ = d_in[4];
    const void* Rf  = d_in[5];
    const void* rbf = d_in[6];
    const void* Wi  = d_in[7];
    const void* bi_ = d_in[8];
    const void* Ri  = d_in[9];
    const void* rbi = d_in[10];
    const void* Wg  = d_in[11];
    const void* bg_ = d_in[12];
    const void* Rg  = d_in[13];
    const void* rbg = d_in[14];
    // d_in[15..18] = Wo, bo, Ro, rbo — dead in the reference, never read.

    // ws layout: xb bf16 [32768][1024] (64 MB) | wb bf16 [3][1024][1024] (6 MB) | rt fp32 (768 KB)
    const size_t NEED = 67108864ull + 6291456ull + 786432ull;
    if (ws_size >= NEED) {
        unsigned short* xb = (unsigned short*)d_ws;
        unsigned short* wbp = xb + 33554432ull;
        float* rt = (float*)(wbp + 3145728ull);
        prep_fused<<<dim3(18112), 256, 0, stream>>>(x, Wf, Wi, Wg, h0,
                                                    Rf, rbf, bf_, Ri, rbi, bi_, Rg, rbg, bg_,
                                                    xb, wbp, rt);
        lstm_main4<<<dim3(16, 256), 256, 0, stream>>>(x, c0, xb, wbp, rt, d_out);
    } else {
        float* rt = (float*)d_ws;
        rprep_kernel<<<dim3(4, 8, 3), 256, 0, stream>>>(x, h0, Rf, rbf, bf_, Ri, rbi, bi_, Rg, rbg, bg_, rt);
        lstm_main<<<dim3(16, 256), 256, 0, stream>>>(x, c0, Wf, Wi, Wg, rt, d_out);
    }
}

// Round 5
// 589.472 us; speedup vs baseline: 1.0947x; 1.0524x over previous
//
#include <hip/hip_runtime.h>
#include <cstdint>

// Problem: B=64, T=512, I=K=1024, H=1024.
// Reference collapses to: rtot_z = h0@R_z^T + rb_z + b_z  (z in {f,i,g}; o-gate dead)
//   gate_z[m',h] = x_perm[m'] . W_z^T + rtot_z[b,h]   with m' = t*64 + b
//   c = sig(f)*c0 + sig(i)*tanh(g); hidden[h, m'] = tanh(c); last-t -> h_last, c_last.
//
// v6 this round: v4/v3 both paid occupancy for schedule depth and lost (m114:
// inter-block TLP already hides what pipelining adds; only constant-occupancy
// pipelining can win). lstm_main5 = main2 geometry EXACTLY (128m x 64h x 3g,
// 4 waves, 40960 B LDS, ~2.6-3 blk/CU) but BK=32 double-buffered WITHIN the
// same 40 KB: 2 x (A 8KB + 3x B 4KB). Per kt: issue 5 gl_lds16 for kt+1 into
// other half -> read frags -> 24 MFMA -> vmcnt(0) -> one raw s_barrier.
// Same barrier count as main2 (32), but the drain now sits after ~10 ds_read
// + 24 MFMA of cover instead of exposing full load latency.
// Swizzle for 64B rows: phys chunk = kc ^ ((row>>1)&3) -> 2-way banks (free).
// prep_fused unchanged. ~220us/iter is fixed harness reset overhead.

typedef short s16x8 __attribute__((ext_vector_type(8)));
typedef short s16x4 __attribute__((ext_vector_type(4)));
typedef float f32x4 __attribute__((ext_vector_type(4)));

static __device__ __forceinline__ float bf2f(unsigned short u) {
    union { unsigned int i; float f; } v; v.i = ((unsigned int)u) << 16; return v.f;
}
static __device__ __forceinline__ unsigned short f2bf(float f) {
    union { float f; unsigned int i; } v; v.f = f;
    unsigned int u = v.i;
    return (unsigned short)((u + 0x7fffu + ((u >> 16) & 1u)) >> 16);
}
static __device__ __forceinline__ float sigm_(float x) { return 1.0f / (1.0f + __expf(-x)); }
static __device__ __forceinline__ float tanh_(float x) { return 1.0f - 2.0f / (1.0f + __expf(2.0f * x)); }

// Detect fp32 vs bf16 storage (wave-uniform, deterministic).
static __device__ __forceinline__ int detect_f32(const void* x) {
    const unsigned int* u = (const unsigned int*)x;
    int c = 0;
#pragma unroll
    for (int i = 0; i < 16; ++i) {
        unsigned int e = (u[i] >> 23) & 255u;
        c += (e >= 100u && e <= 140u) ? 1 : 0;
    }
    return c >= 8;
}

static __device__ __forceinline__ float ldsc(const void* p, int i, int f32) {
    return f32 ? ((const float*)p)[i] : bf2f(((const unsigned short*)p)[i]);
}

static __device__ __forceinline__ float4 load4f(const void* p, size_t eoff, int f32) {
    if (f32) return *(const float4*)((const float*)p + eoff);
    s16x4 v = *(const s16x4*)((const unsigned short*)p + eoff);
    return make_float4(bf2f((unsigned short)v[0]), bf2f((unsigned short)v[1]),
                       bf2f((unsigned short)v[2]), bf2f((unsigned short)v[3]));
}

// 16B direct global->LDS. LDS dest linear in lane order (uniform base + lane*16).
static __device__ __forceinline__ void gl_lds16(const void* g, void* l) {
    __builtin_amdgcn_global_load_lds(
        (const __attribute__((address_space(1))) unsigned int*)g,
        (__attribute__((address_space(3))) unsigned int*)l, 16, 0, 0);
}

// ---------------- fused prep: linear bf16 convert of x,W  +  rprep ----------------
__global__ __launch_bounds__(256) void prep_fused(
    const void* __restrict__ x,
    const void* __restrict__ Wf, const void* __restrict__ Wi, const void* __restrict__ Wg,
    const void* __restrict__ h0,
    const void* __restrict__ Rf, const void* __restrict__ rbf, const void* __restrict__ bf_,
    const void* __restrict__ Ri, const void* __restrict__ rbi, const void* __restrict__ bi_,
    const void* __restrict__ Rg, const void* __restrict__ rbg, const void* __restrict__ bg_,
    unsigned short* __restrict__ xb, unsigned short* __restrict__ wb,
    float* __restrict__ rt)
{
    __shared__ float h0l[64][132];
    __shared__ float Rl[16][132];
    const int f32 = detect_f32(x);
    const int tid = threadIdx.x;
    const int bid = blockIdx.x;

    if (bid < 17920) {
        const int r = bid * 2 + (tid >> 7);
        const int c = (tid & 127) << 3;
        const void* src;
        size_t soff;
        unsigned short* dst;
        if (r < 32768) {
            src = x;
            soff = ((size_t)r << 10) + c;
            dst = xb + soff;
        } else {
            const int wr = r - 32768;
            const int g = wr >> 10;
            src = (g == 0) ? Wf : (g == 1) ? Wi : Wg;
            soff = ((size_t)(wr & 1023) << 10) + c;
            dst = wb + ((size_t)wr << 10) + c;
        }
        if (f32) {
            const float* s = (const float*)src + soff;
            float4 u0 = *(const float4*)s;
            float4 u1 = *(const float4*)(s + 4);
            s16x8 v;
            v[0] = (short)f2bf(u0.x); v[1] = (short)f2bf(u0.y);
            v[2] = (short)f2bf(u0.z); v[3] = (short)f2bf(u0.w);
            v[4] = (short)f2bf(u1.x); v[5] = (short)f2bf(u1.y);
            v[6] = (short)f2bf(u1.z); v[7] = (short)f2bf(u1.w);
            *(s16x8*)dst = v;
        } else {
            *(s16x8*)dst = *(const s16x8*)((const unsigned short*)src + soff);
        }
        return;
    }

    const int pb = bid - 17920;
    const int z  = pb >> 6;
    const int hb = (pb & 63) * 16;
    const void* R  = (z == 0) ? Rf  : (z == 1) ? Ri  : Rg;
    const void* rb = (z == 0) ? rbf : (z == 1) ? rbi : rbg;
    const void* bb = (z == 0) ? bf_ : (z == 1) ? bi_ : bg_;
    const int hl = tid >> 4;
    const int bq = tid & 15;
    float acc[4] = {0.f, 0.f, 0.f, 0.f};

    for (int k0 = 0; k0 < 1024; k0 += 128) {
#pragma unroll
        for (int i = 0; i < 8; ++i) {
            int lin = i * 256 + tid;
            int r = lin >> 5, c4 = lin & 31;
            *(float4*)&h0l[r][c4 * 4] = load4f(h0, (size_t)r * 1024 + k0 + c4 * 4, f32);
        }
#pragma unroll
        for (int i = 0; i < 2; ++i) {
            int lin = i * 256 + tid;
            int r = lin >> 5, c4 = lin & 31;
            *(float4*)&Rl[r][c4 * 4] = load4f(R, (size_t)(hb + r) * 1024 + k0 + c4 * 4, f32);
        }
        __syncthreads();
#pragma unroll 8
        for (int k4 = 0; k4 < 32; ++k4) {
            float4 rv = *(const float4*)&Rl[hl][k4 * 4];
#pragma unroll
            for (int j = 0; j < 4; ++j) {
                float4 hv = *(const float4*)&h0l[bq + j * 16][k4 * 4];
                acc[j] += rv.x * hv.x + rv.y * hv.y + rv.z * hv.z + rv.w * hv.w;
            }
        }
        __syncthreads();
    }
    float extra = ldsc(rb, hb + hl, f32) + ldsc(bb, hb + hl, f32);
    float* outz = rt + (size_t)z * 65536;
#pragma unroll
    for (int j = 0; j < 4; ++j)
        outz[(size_t)(bq + j * 16) * 1024 + hb + hl] = acc[j] + extra;
}

// ---------------- main fused GEMM v6: BK=32 double-buffer in main2's 40KB ----------------
// Tile 128 m' x 64 h x 3 gates, 4 waves 2x2, 256 threads.
// LDS: 2 x (A 8KB + Bf/Bi/Bg 4KB each) = 40960 B -> same occupancy as main2.
// Per kt (32 steps of K=32): issue 5 gl_lds16 for kt+1 into other half ->
// 10 ds_read_b128 -> 24 MFMA -> vmcnt(0) -> one raw s_barrier.
__global__ __launch_bounds__(256, 2) void lstm_main5(
    const void* __restrict__ x,                  // dtype detect only
    const void* __restrict__ c0,
    const unsigned short* __restrict__ xb,       // [64][512][1024] bf16 (native layout)
    const unsigned short* __restrict__ wb,       // [3][1024][1024] bf16
    const float* __restrict__ rt,
    void* __restrict__ dout)
{
    __shared__ __align__(16) unsigned char smem[40960];

    const int f32 = detect_f32(x);
    const int tid  = threadIdx.x;
    const int lane = tid & 63;
    const int w    = tid >> 6;
    const int wm   = w >> 1;
    const int wn   = w & 1;
    const int col  = lane & 15;
    const int quad = lane >> 4;

    // XCD-pinning block swizzle: XCD = L%8 owns h-tiles {2x,2x+1}; m-tiles sweep.
    const int L    = blockIdx.x + (blockIdx.y << 4);   // grid (16, 256)
    const int xcd  = L & 7;
    const int s    = L >> 3;
    const int hblk = (xcd << 1) | (s & 1);
    const int mblk = s >> 1;
    const int m0   = mblk << 7;
    const int h0t  = hblk << 6;

    // staging descriptors: 16B chunks; LDS linear; global source pre-swizzled.
    // BK=32 rows are 64B = 4 chunks; phys chunk kc holds global chunk kc^((row>>1)&3).
    // A: 512 chunks -> 2/thread; row = ci>>2 (0..127), kc = ci&3.
    int   cA[2]; size_t gA[2];
#pragma unroll
    for (int i = 0; i < 2; ++i) {
        const int ci = tid + (i << 8);
        const int row = ci >> 2, kc = ci & 3;
        const int mg = m0 + row;
        const int xrow = ((mg & 63) << 9) + (mg >> 6);   // m' -> (b,t) native row
        cA[i] = ci << 4;
        gA[i] = ((size_t)xrow << 10) + (size_t)((kc ^ ((row >> 1) & 3)) << 3);
    }
    // B (per gate): 256 chunks -> 1/thread; row = tid>>2 (0..63), kc = tid&3.
    {
    }
    const int brow = tid >> 2, bkc = tid & 3;
    const int cBd  = tid << 4;
    const size_t gB = ((size_t)(h0t + brow) << 10) + (size_t)((bkc ^ ((brow >> 1) & 3)) << 3);

    // fragment read bases: rows of 64B; phys granule = quad ^ ((col>>1)&3)
    // (row = 16-aligned base + col; base>>1 is 0 mod 4 for both A and B rows).
    const int xbits2 = ((col >> 1) & 3) << 4;
    int aRow[4], bRow[2];
#pragma unroll
    for (int mi = 0; mi < 4; ++mi) aRow[mi] = (wm * 64 + mi * 16 + col) << 6;
#pragma unroll
    for (int ni = 0; ni < 2; ++ni) bRow[ni] = (wn * 32 + ni * 16 + col) << 6;
    const int cb = (quad << 4) ^ xbits2;

    const unsigned short* wf = wb;
    const unsigned short* wi = wb + 1048576;
    const unsigned short* wg = wb + 2097152;

    f32x4 aF[4][2], aI[4][2], aG[4][2];
#pragma unroll
    for (int mi = 0; mi < 4; ++mi)
#pragma unroll
        for (int ni = 0; ni < 2; ++ni) {
            aF[mi][ni] = (f32x4)0.f; aI[mi][ni] = (f32x4)0.f; aG[mi][ni] = (f32x4)0.f;
        }

    // ---- prologue: stage K-step 0 into buf0, drain, sync ----
#pragma unroll
    for (int i = 0; i < 2; ++i) gl_lds16(xb + gA[i], smem + cA[i]);
    gl_lds16(wf + gB, smem + 8192 + cBd);
    gl_lds16(wi + gB, smem + 12288 + cBd);
    gl_lds16(wg + gB, smem + 16384 + cBd);
    asm volatile("s_waitcnt vmcnt(0)" ::: "memory");
    __builtin_amdgcn_s_barrier();

    unsigned cur = 0;                            // byte offset of current half
    for (int kt = 0; kt < 32; ++kt) {
        const unsigned nb0 = cur ^ 20480u;
        // ---- issue next K-step staging first (cover: 10 ds_read + 24 MFMA) ----
        if (kt < 31) {
            const size_t k0n = (size_t)(kt + 1) << 5;
#pragma unroll
            for (int i = 0; i < 2; ++i) gl_lds16(xb + gA[i] + k0n, smem + nb0 + cA[i]);
            gl_lds16(wf + gB + k0n, smem + nb0 + 8192 + cBd);
            gl_lds16(wi + gB + k0n, smem + nb0 + 12288 + cBd);
            gl_lds16(wg + gB + k0n, smem + nb0 + 16384 + cBd);
        }
        // ---- compute current K-step: 10 ds_read_b128, 24 MFMA ----
        {
            s16x8 av[4], bfv[2], biv[2], bgv[2];
#pragma unroll
            for (int mi = 0; mi < 4; ++mi)
                av[mi] = *(const s16x8*)(smem + cur + aRow[mi] + cb);
#pragma unroll
            for (int ni = 0; ni < 2; ++ni) {
                bfv[ni] = *(const s16x8*)(smem + cur + 8192  + bRow[ni] + cb);
                biv[ni] = *(const s16x8*)(smem + cur + 12288 + bRow[ni] + cb);
                bgv[ni] = *(const s16x8*)(smem + cur + 16384 + bRow[ni] + cb);
            }
#pragma unroll
            for (int mi = 0; mi < 4; ++mi)
#pragma unroll
                for (int ni = 0; ni < 2; ++ni) {
                    aF[mi][ni] = __builtin_amdgcn_mfma_f32_16x16x32_bf16(av[mi], bfv[ni], aF[mi][ni], 0, 0, 0);
                    aI[mi][ni] = __builtin_amdgcn_mfma_f32_16x16x32_bf16(av[mi], biv[ni], aI[mi][ni], 0, 0, 0);
                    aG[mi][ni] = __builtin_amdgcn_mfma_f32_16x16x32_bf16(av[mi], bgv[ni], aG[mi][ni], 0, 0, 0);
                }
        }
        // ---- close kt: prefetch had the whole compute phase to land ----
        asm volatile("s_waitcnt vmcnt(0)" ::: "memory");
        __builtin_amdgcn_s_barrier();
        cur = nb0;
    }

    // ---- epilogue (identical math to main2) ----
    const float* rtF = rt;
    const float* rtI = rt + 65536;
    const float* rtG = rt + 131072;
    unsigned short* outHb = (unsigned short*)dout;
    unsigned short* outHlb = outHb + 33554432;
    unsigned short* outClb = outHlb + 65536;
    float* outHf = (float*)dout;
    float* outHlf = outHf + 33554432;
    float* outClf = outHlf + 65536;

#pragma unroll
    for (int mi = 0; mi < 4; ++mi) {
#pragma unroll
        for (int ni = 0; ni < 2; ++ni) {
            const int hl = wn * 32 + ni * 16 + col;
            const int h  = h0t + hl;
            const int mbase = wm * 64 + mi * 16 + quad * 4;
            s16x4 packb;
            float4 packf;
#pragma unroll
            for (int r = 0; r < 4; ++r) {
                const int mg = m0 + mbase + r;
                const int b  = mg & 63;
                const int idx = b * 1024 + h;
                float pf = aF[mi][ni][r] + rtF[idx];
                float pi = aI[mi][ni][r] + rtI[idx];
                float pg = aG[mi][ni][r] + rtG[idx];
                float fv = sigm_(pf);
                float iv = sigm_(pi);
                float gv = tanh_(pg);
                float cv = fv * ldsc(c0, idx, f32) + iv * gv;
                float hv = tanh_(cv);
                if (r == 0) { packf.x = hv; } else if (r == 1) { packf.y = hv; }
                else if (r == 2) { packf.z = hv; } else { packf.w = hv; }
                packb[r] = (short)f2bf(hv);
                if ((mg >> 6) == 511) {          // t == T-1
                    if (f32) { outHlf[idx] = hv; outClf[idx] = cv; }
                    else     { outHlb[idx] = f2bf(hv); outClb[idx] = f2bf(cv); }
                }
            }
            if (f32) {
                float* ldsTf = (float*)(smem + (size_t)hl * 528);
                *(float4*)(ldsTf + mbase) = packf;
            } else {
                *(s16x4*)(smem + (size_t)hl * 272 + mbase * 2) = packb;
            }
        }
    }
    __syncthreads();

    const int hl = tid >> 2;
    const int ch = tid & 3;
    if (f32) {
        float* obase = outHf + (size_t)(h0t + hl) * 32768 + m0 + ch * 32;
        const unsigned char* trow = smem + (size_t)hl * 528 + ch * 128;
#pragma unroll
        for (int j = 0; j < 8; ++j)
            *(float4*)(obase + j * 4) = *(const float4*)(trow + j * 16);
    } else {
        unsigned short* obase = outHb + (size_t)(h0t + hl) * 32768 + m0 + ch * 32;
        const unsigned char* trow = smem + (size_t)hl * 272 + ch * 64;
#pragma unroll
        for (int j = 0; j < 4; ++j)
            *(s16x8*)(obase + j * 8) = *(const s16x8*)(trow + j * 16);
    }
}

// ================= v1 fallback (workspace too small) =================
static __device__ __forceinline__ void stage8(const void* base, size_t eoff, short* dst, int f32) {
    if (f32) {
        const float* s = (const float*)base + eoff;
        float4 u0 = *(const float4*)s;
        float4 u1 = *(const float4*)(s + 4);
        s16x8 v;
        v[0] = (short)f2bf(u0.x); v[1] = (short)f2bf(u0.y);
        v[2] = (short)f2bf(u0.z); v[3] = (short)f2bf(u0.w);
        v[4] = (short)f2bf(u1.x); v[5] = (short)f2bf(u1.y);
        v[6] = (short)f2bf(u1.z); v[7] = (short)f2bf(u1.w);
        *(s16x8*)dst = v;
    } else {
        *(s16x8*)dst = *(const s16x8*)((const unsigned short*)base + eoff);
    }
}

__global__ __launch_bounds__(256) void rprep_kernel(
    const void* __restrict__ xdet,
    const void* __restrict__ h0,
    const void* __restrict__ Rf, const void* __restrict__ rbf, const void* __restrict__ bf_,
    const void* __restrict__ Ri, const void* __restrict__ rbi, const void* __restrict__ bi_,
    const void* __restrict__ Rg, const void* __restrict__ rbg, const void* __restrict__ bg_,
    float* __restrict__ rt)
{
    const int f32 = detect_f32(xdet);
    __shared__ float h0f[8][1024];
    const int tid = threadIdx.x;
    const int b0 = blockIdx.y * 8;
    const int z  = blockIdx.z;
    for (int idx = tid; idx < 8 * 1024; idx += 256) {
        int r = idx >> 10, k = idx & 1023;
        h0f[r][k] = ldsc(h0, (b0 + r) * 1024 + k, f32);
    }
    __syncthreads();
    const void* R  = (z == 0) ? Rf  : (z == 1) ? Ri  : Rg;
    const void* rb = (z == 0) ? rbf : (z == 1) ? rbi : rbg;
    const void* bb = (z == 0) ? bf_ : (z == 1) ? bi_ : bg_;
    const int h = blockIdx.x * 256 + tid;
    float acc[8];
#pragma unroll
    for (int i = 0; i < 8; ++i) acc[i] = 0.f;
    for (int k0 = 0; k0 < 1024; k0 += 8) {
        float rf[8];
        if (f32) {
            const float* Rrow = (const float*)R + (size_t)h * 1024;
            float4 a = *(const float4*)(Rrow + k0);
            float4 b = *(const float4*)(Rrow + k0 + 4);
            rf[0] = a.x; rf[1] = a.y; rf[2] = a.z; rf[3] = a.w;
            rf[4] = b.x; rf[5] = b.y; rf[6] = b.z; rf[7] = b.w;
        } else {
            const unsigned short* Rrow = (const unsigned short*)R + (size_t)h * 1024;
            s16x8 rv = *(const s16x8*)(Rrow + k0);
#pragma unroll
            for (int j = 0; j < 8; ++j) rf[j] = bf2f((unsigned short)rv[j]);
        }
#pragma unroll
        for (int b = 0; b < 8; ++b) {
            float4 u0 = *(const float4*)&h0f[b][k0];
            float4 u1 = *(const float4*)&h0f[b][k0 + 4];
            acc[b] += rf[0] * u0.x + rf[1] * u0.y + rf[2] * u0.z + rf[3] * u0.w
                    + rf[4] * u1.x + rf[5] * u1.y + rf[6] * u1.z + rf[7] * u1.w;
        }
    }
    float extra = ldsc(rb, h, f32) + ldsc(bb, h, f32);
    float* outz = rt + (size_t)z * 65536;
#pragma unroll
    for (int b = 0; b < 8; ++b) outz[(b0 + b) * 1024 + h] = acc[b] + extra;
}

__global__ __launch_bounds__(256, 2) void lstm_main(
    const void* __restrict__ x,
    const void* __restrict__ c0,
    const void* __restrict__ Wf,
    const void* __restrict__ Wi,
    const void* __restrict__ Wg,
    const float* __restrict__ rt,
    void* __restrict__ dout)
{
    __shared__ __align__(16) unsigned char smem[33792];
    short* smA  = (short*)smem;
    short* smBf = (short*)(smem + 8192);
    short* smBi = (short*)(smem + 12288);
    short* smBg = (short*)(smem + 16384);

    const int f32 = detect_f32(x);
    const int tid  = threadIdx.x;
    const int lane = tid & 63;
    const int w    = tid >> 6;
    const int wm   = w >> 1;
    const int wn   = w & 1;
    const int col  = lane & 15;
    const int quad = lane >> 4;

    const int m0  = blockIdx.y * 128;
    const int h0t = blockIdx.x * 64;

    const int cA0 = tid, cA1 = tid + 256;
    const int mgA0 = m0 + (cA0 >> 2), mgA1 = m0 + (cA1 >> 2);
    size_t aoff0 = (size_t)((mgA0 & 63) * 512 + (mgA0 >> 6)) * 1024 + (cA0 & 3) * 8;
    size_t aoff1 = (size_t)((mgA1 & 63) * 512 + (mgA1 >> 6)) * 1024 + (cA1 & 3) * 8;
    size_t boff = (size_t)(h0t + (tid >> 2)) * 1024 + (tid & 3) * 8;
    short* dA0 = smA  + cA0 * 8;
    short* dA1 = smA  + cA1 * 8;
    short* dBf = smBf + tid * 8;
    short* dBi = smBi + tid * 8;
    short* dBg = smBg + tid * 8;

    const short* aBase  = smA  + (wm * 64 + col) * 32 + quad * 8;
    const short* bfBase = smBf + (wn * 32 + col) * 32 + quad * 8;
    const short* biBase = smBi + (wn * 32 + col) * 32 + quad * 8;
    const short* bgBase = smBg + (wn * 32 + col) * 32 + quad * 8;

    f32x4 aF[4][2], aI[4][2], aG[4][2];
#pragma unroll
    for (int mi = 0; mi < 4; ++mi)
#pragma unroll
        for (int ni = 0; ni < 2; ++ni) {
            aF[mi][ni] = (f32x4)0.f; aI[mi][ni] = (f32x4)0.f; aG[mi][ni] = (f32x4)0.f;
        }

    for (int kt = 0; kt < 32; ++kt) {
        const size_t ko = (size_t)kt * 32;
        stage8(x,  aoff0 + ko, dA0, f32);
        stage8(x,  aoff1 + ko, dA1, f32);
        stage8(Wf, boff  + ko, dBf, f32);
        stage8(Wi, boff  + ko, dBi, f32);
        stage8(Wg, boff  + ko, dBg, f32);
        __syncthreads();

        s16x8 av[4], bfv[2], biv[2], bgv[2];
#pragma unroll
        for (int mi = 0; mi < 4; ++mi) av[mi] = *(const s16x8*)(aBase + mi * 512);
#pragma unroll
        for (int ni = 0; ni < 2; ++ni) {
            bfv[ni] = *(const s16x8*)(bfBase + ni * 512);
            biv[ni] = *(const s16x8*)(biBase + ni * 512);
            bgv[ni] = *(const s16x8*)(bgBase + ni * 512);
        }
#pragma unroll
        for (int mi = 0; mi < 4; ++mi)
#pragma unroll
            for (int ni = 0; ni < 2; ++ni) {
                aF[mi][ni] = __builtin_amdgcn_mfma_f32_16x16x32_bf16(av[mi], bfv[ni], aF[mi][ni], 0, 0, 0);
                aI[mi][ni] = __builtin_amdgcn_mfma_f32_16x16x32_bf16(av[mi], biv[ni], aI[mi][ni], 0, 0, 0);
                aG[mi][ni] = __builtin_amdgcn_mfma_f32_16x16x32_bf16(av[mi], bgv[ni], aG[mi][ni], 0, 0, 0);
            }
        __syncthreads();
    }

    const float* rtF = rt;
    const float* rtI = rt + 65536;
    const float* rtG = rt + 131072;
    unsigned short* outHb = (unsigned short*)dout;
    unsigned short* outHlb = outHb + 33554432;
    unsigned short* outClb = outHlb + 65536;
    float* outHf = (float*)dout;
    float* outHlf = outHf + 33554432;
    float* outClf = outHlf + 65536;

#pragma unroll
    for (int mi = 0; mi < 4; ++mi) {
#pragma unroll
        for (int ni = 0; ni < 2; ++ni) {
            const int hl = wn * 32 + ni * 16 + col;
            const int h  = h0t + hl;
            const int mbase = wm * 64 + mi * 16 + quad * 4;
            s16x4 packb;
            float4 packf;
#pragma unroll
            for (int r = 0; r < 4; ++r) {
                const int mg = m0 + mbase + r;
                const int b  = mg & 63;
                const int idx = b * 1024 + h;
                float pf = aF[mi][ni][r] + rtF[idx];
                float pi = aI[mi][ni][r] + rtI[idx];
                float pg = aG[mi][ni][r] + rtG[idx];
                float fv = sigm_(pf);
                float iv = sigm_(pi);
                float gv = tanh_(pg);
                float cv = fv * ldsc(c0, idx, f32) + iv * gv;
                float hv = tanh_(cv);
                if (r == 0) { packf.x = hv; } else if (r == 1) { packf.y = hv; }
                else if (r == 2) { packf.z = hv; } else { packf.w = hv; }
                packb[r] = (short)f2bf(hv);
                if ((mg >> 6) == 511) {
                    if (f32) { outHlf[idx] = hv; outClf[idx] = cv; }
                    else     { outHlb[idx] = f2bf(hv); outClb[idx] = f2bf(cv); }
                }
            }
            if (f32) {
                float* ldsTf = (float*)(smem + (size_t)hl * 528);
                *(float4*)(ldsTf + mbase) = packf;
            } else {
                *(s16x4*)(smem + (size_t)hl * 272 + mbase * 2) = packb;
            }
        }
    }
    __syncthreads();

    const int hl = tid >> 2;
    const int ch = tid & 3;
    if (f32) {
        float* obase = outHf + (size_t)(h0t + hl) * 32768 + m0 + ch * 32;
        const unsigned char* trow = smem + (size_t)hl * 528 + ch * 128;
#pragma unroll
        for (int j = 0; j < 8; ++j)
            *(float4*)(obase + j * 4) = *(const float4*)(trow + j * 16);
    } else {
        unsigned short* obase = outHb + (size_t)(h0t + hl) * 32768 + m0 + ch * 32;
        const unsigned char* trow = smem + (size_t)hl * 272 + ch * 64;
#pragma unroll
        for (int j = 0; j < 4; ++j)
            *(s16x8*)(obase + j * 8) = *(const s16x8*)(trow + j * 16);
    }
}

extern "C" void kernel_launch(void* const* d_in, const int* in_sizes, int n_in,
                              void* d_out, int out_size, void* d_ws, size_t ws_size,
                              hipStream_t stream) {
    (void)in_sizes; (void)n_in; (void)out_size;
    const void* x   = d_in[0];
    const void* h0  = d_in[1];
    const void* c0  = d_in[2];
    const void* Wf  = d_in[3];
    const void* bf_ = d_in[4];
    const void* Rf  = d_in[5];
    const void* rbf = d_in[6];
    const void* Wi  = d_in[7];
    const void* bi_ = d_in[8];
    const void* Ri  = d_in[9];
    const void* rbi = d_in[10];
    const void* Wg  = d_in[11];
    const void* bg_ = d_in[12];
    const void* Rg  = d_in[13];
    const void* rbg = d_in[14];
    // d_in[15..18] = Wo, bo, Ro, rbo — dead in the reference, never read.

    // ws layout: xb bf16 [32768][1024] (64 MB) | wb bf16 [3][1024][1024] (6 MB) | rt fp32 (768 KB)
    const size_t NEED = 67108864ull + 6291456ull + 786432ull;
    if (ws_size >= NEED) {
        unsigned short* xb = (unsigned short*)d_ws;
        unsigned short* wbp = xb + 33554432ull;
        float* rt = (float*)(wbp + 3145728ull);
        prep_fused<<<dim3(18112), 256, 0, stream>>>(x, Wf, Wi, Wg, h0,
                                                    Rf, rbf, bf_, Ri, rbi, bi_, Rg, rbg, bg_,
                                                    xb, wbp, rt);
        lstm_main5<<<dim3(16, 256), 256, 0, stream>>>(x, c0, xb, wbp, rt, d_out);
    } else {
        float* rt = (float*)d_ws;
        rprep_kernel<<<dim3(4, 8, 3), 256, 0, stream>>>(x, h0, Rf, rbf, bf_, Ri, rbi, bi_, Rg, rbg, bg_, rt);
        lstm_main<<<dim3(16, 256), 256, 0, stream>>>(x, c0, Wf, Wi, Wg, rt, d_out);
    }
}